// Round 1
// baseline (544.393 us; speedup 1.0000x reference)
//
#include <hip/hip_runtime.h>

#define NN 20
#define N2 400
#define MM 440
#define NITERS 25

__device__ __forceinline__ double wave_sum(double v) {
  #pragma unroll
  for (int off = 32; off > 0; off >>= 1) v += __shfl_xor(v, off, 64);
  return v;
}
__device__ __forceinline__ double wave_min(double v) {
  #pragma unroll
  for (int off = 32; off > 0; off >>= 1) v = fmin(v, __shfl_xor(v, off, 64));
  return v;
}

__device__ __forceinline__ double fair_c(int c) {
  // matches fp32 reference: IDX_A/8 - (1-IDX_A)/12 computed in float
  return (c < 8) ? 0.125 : (double)(-1.0f / 12.0f);
}

__global__ __launch_bounds__(64, 1) void ipm_kernel(const float* __restrict__ x,
                                                    float* __restrict__ out) {
  const int b = blockIdx.x;
  const int t = threadIdx.x;

  __shared__ double z[N2], p[N2], phi[N2], phiD[N2], y1[N2], w1[N2], w2[N2], dz[N2];
  __shared__ double s[MM], lam[MM], dvec[MM], rpri[MM], g[MM], dsv_[MM], dlv_[MM];
  __shared__ double Smat[N2];
  __shared__ double rowsum[NN], colsum[NN], p1[NN], t1v[NN], p2[NN], Cc[NN];
  __shared__ double D1i[NN], D2v[NN], rb1[NN], rb2[NN], be1[NN], be2[NN], a1r[NN], a2r[NN];
  __shared__ double sc[8]; // 0:nu 1:mu 2:req 3:dnu 4:alpha

  const double EPSd = 1e-4, SIG = 0.1;

  // ---- init: z = 0.5/N, s = h - G z, lam = 1, nu = 0
  for (int i = t; i < N2; i += 64) {
    z[i] = 0.025;
    p[i] = -(double)x[b * N2 + i];
  }
  for (int k = t; k < MM; k += 64) {
    s[k] = (k < 2 * NN) ? 0.5 : 0.025;
    lam[k] = 1.0;
  }
  if (t == 0) sc[0] = 0.0;
  __syncthreads();

  for (int it = 0; it < NITERS; ++it) {
    // ---- Phase A: row/col sums of z; mu; r_eq
    double lmu = 0.0, lreq = 0.0;
    for (int k = t; k < MM; k += 64) lmu += s[k] * lam[k];
    for (int i = t; i < N2; i += 64) lreq += fair_c(i % NN) * z[i];
    lmu = wave_sum(lmu);
    lreq = wave_sum(lreq);
    if (t < NN) {
      double sr = 0.0, scl = 0.0;
      for (int j = 0; j < NN; ++j) { sr += z[t * NN + j]; scl += z[j * NN + t]; }
      rowsum[t] = sr; colsum[t] = scl;
    }
    if (t == 0) { sc[1] = lmu / MM; sc[2] = lreq; }
    __syncthreads();
    const double mu = sc[1], nu = sc[0], req = sc[2];

    // ---- Phase C: d = lam/s, r_pri, g = SIG*mu/s - lam + d*r_pri
    for (int k = t; k < MM; k += 64) {
      double dd = lam[k] / s[k];
      dvec[k] = dd;
      double gz = (k < NN) ? rowsum[k] : (k < 2 * NN) ? colsum[k - NN] : -z[k - 2 * NN];
      double h = (k < 2 * NN) ? 1.0 : 0.0;
      double rp = gz + s[k] - h;
      rpri[k] = rp;
      g[k] = SIG * mu / s[k] - lam[k] + dd * rp;
    }
    __syncthreads();

    // ---- Phase D: phi = 1/(EPS + d_slack), y1 = rhs_z
    for (int i = t; i < N2; i += 64) {
      int r = i / NN, c = i % NN;
      double ac = fair_c(c);
      double ph = 1.0 / (EPSd + dvec[2 * NN + i]);
      phi[i] = ph;
      double rd = EPSd * z[i] + p[i] + lam[r] + lam[NN + c] - lam[2 * NN + i] + nu * ac;
      y1[i] = -(rd + g[r] + g[NN + c] - g[2 * NN + i]);
    }
    __syncthreads();

    // ---- Phase E: row/col reductions over phi
    if (t < NN) {
      double Rr = 0, Ccl = 0, pp1 = 0, tt1 = 0, pp2 = 0;
      for (int j = 0; j < NN; ++j) {
        double phr = phi[t * NN + j];
        double phc = phi[j * NN + t];
        Rr += phr; Ccl += phc;
        pp1 += phr * y1[t * NN + j];
        tt1 += phc * y1[j * NN + t];
        pp2 += phr * fair_c(j);
      }
      D1i[t] = 1.0 / (1.0 / dvec[t] + Rr);
      Cc[t] = Ccl;
      D2v[t] = 1.0 / dvec[NN + t] + Ccl;
      p1[t] = pp1; t1v[t] = tt1; p2[t] = pp2;
    }
    __syncthreads();

    // ---- Phase F: phiD = phi / D1_row
    for (int i = t; i < N2; i += 64) phiD[i] = phi[i] * D1i[i / NN];
    __syncthreads();

    // ---- Phase G: Schur complement S = D2 - Phi^T D1^-1 Phi, and beta-RHS
    for (int e = t; e < N2; e += 64) {
      int c = e / NN, cp = e % NN;
      double acc = 0.0;
      for (int r = 0; r < NN; ++r) acc += phiD[r * NN + c] * phi[r * NN + cp];
      double Sv = -acc;
      if (c == cp) Sv += D2v[c];
      Smat[e] = Sv;
    }
    if (t < NN) {
      double acc1 = 0.0, acc2 = 0.0;
      for (int r = 0; r < NN; ++r) {
        double pd = phiD[r * NN + t];
        acc1 += pd * p1[r];
        acc2 += pd * p2[r];
      }
      rb1[t] = t1v[t] - acc1;
      rb2[t] = fair_c(t) * Cc[t] - acc2;
    }
    __syncthreads();

    // ---- Phase H: in-wave augmented Gauss-Jordan (lanes 0..19 = S cols, 20/21 = RHS)
    {
      double B[NN];
      #pragma unroll
      for (int i = 0; i < NN; ++i) {
        double v = 0.0;
        if (t < NN) v = Smat[i * NN + t];
        else if (t == NN) v = rb1[i];
        else if (t == NN + 1) v = rb2[i];
        B[i] = v;
      }
      #pragma unroll
      for (int k = 0; k < NN; ++k) {
        double piv = __shfl(B[k], k, 64);
        double dinv = 1.0 / piv;
        double colk[NN];
        #pragma unroll
        for (int i = 0; i < NN; ++i) colk[i] = __shfl(B[i], k, 64);
        double rk = B[k] * dinv;
        #pragma unroll
        for (int i = 0; i < NN; ++i)
          if (i != k) B[i] -= colk[i] * rk;
        B[k] = rk;
      }
      if (t == NN) {
        #pragma unroll
        for (int i = 0; i < NN; ++i) be1[i] = B[i];
      }
      if (t == NN + 1) {
        #pragma unroll
        for (int i = 0; i < NN; ++i) be2[i] = B[i];
      }
    }
    __syncthreads();

    // ---- Phase I: alpha_row = D1^-1 (p - Phi beta)
    if (t < NN) {
      double acc1 = 0.0, acc2 = 0.0;
      for (int c = 0; c < NN; ++c) {
        double ph = phi[t * NN + c];
        acc1 += ph * be1[c];
        acc2 += ph * be2[c];
      }
      a1r[t] = (p1[t] - acc1) * D1i[t];
      a2r[t] = (p2[t] - acc2) * D1i[t];
    }
    __syncthreads();

    // ---- Phase J: w1 = H^-1 rhs_z, w2 = H^-1 a; dots with a; dnu
    double law1 = 0.0, law2 = 0.0;
    for (int i = t; i < N2; i += 64) {
      int r = i / NN, c = i % NN;
      double ac = fair_c(c);
      double ww1 = phi[i] * (y1[i] - a1r[r] - be1[c]);
      double ww2 = phi[i] * (ac - a2r[r] - be2[c]);
      w1[i] = ww1; w2[i] = ww2;
      law1 += ac * ww1; law2 += ac * ww2;
    }
    law1 = wave_sum(law1);
    law2 = wave_sum(law2);
    if (t == 0) sc[3] = (law1 + req) / law2;
    __syncthreads();
    const double dnu = sc[3];

    // ---- Phase K: dz = w1 - dnu * w2
    for (int i = t; i < N2; i += 64) dz[i] = w1[i] - dnu * w2[i];
    __syncthreads();

    // ---- Phase L: row/col sums of dz
    if (t < NN) {
      double sr = 0.0, scl = 0.0;
      for (int j = 0; j < NN; ++j) { sr += dz[t * NN + j]; scl += dz[j * NN + t]; }
      rowsum[t] = sr; colsum[t] = scl;
    }
    __syncthreads();

    // ---- Phase M: ds, dlam, step length
    double lmin = 1e30;
    for (int k = t; k < MM; k += 64) {
      double gdz = (k < NN) ? rowsum[k] : (k < 2 * NN) ? colsum[k - NN] : -dz[k - 2 * NN];
      double dsv = -rpri[k] - gdz;
      double dlv = (SIG * mu - s[k] * lam[k] - lam[k] * dsv) / s[k];
      dsv_[k] = dsv; dlv_[k] = dlv;
      if (dsv < 0.0) lmin = fmin(lmin, -s[k] / dsv);
      if (dlv < 0.0) lmin = fmin(lmin, -lam[k] / dlv);
    }
    lmin = wave_min(lmin);
    if (t == 0) sc[4] = fmin(1.0, 0.99 * lmin);
    __syncthreads();
    const double a = sc[4];

    // ---- Phase N: updates
    for (int i = t; i < N2; i += 64) z[i] += a * dz[i];
    for (int k = t; k < MM; k += 64) { s[k] += a * dsv_[k]; lam[k] += a * dlv_[k]; }
    if (t == 0) sc[0] = nu + a * dnu;
    __syncthreads();
  }

  for (int i = t; i < N2; i += 64) out[b * N2 + i] = (float)z[i];
}

extern "C" void kernel_launch(void* const* d_in, const int* in_sizes, int n_in,
                              void* d_out, int out_size, void* d_ws, size_t ws_size,
                              hipStream_t stream) {
  const float* x = (const float*)d_in[0];
  float* out = (float*)d_out;
  hipLaunchKernelGGL(ipm_kernel, dim3(32), dim3(64), 0, stream, x, out);
}

// Round 3
// 453.698 us; speedup vs baseline: 1.1999x; 1.1999x over previous
//
#include <hip/hip_runtime.h>

#define NN 20
#define NP 21          // padded row stride for 20x20 fp64 tiles
#define SP 22          // Schur stride: cols 0..19 = S, 20 = rb1, 21 = rb2
#define N2 400
#define MM 440
#define NITERS 25

// single-wave block + per-wave in-order LDS pipeline => compiler fence suffices
#define FENCE() asm volatile("" ::: "memory")

__device__ __forceinline__ double drcp(double x) {
  double r = __builtin_amdgcn_rcp(x);       // v_rcp_f64 approx
  r = fma(r, fma(-x, r, 1.0), r);           // NR 1
  r = fma(r, fma(-x, r, 1.0), r);           // NR 2 -> ~1 ulp
  return r;
}
__device__ __forceinline__ double wsum(double v) {
#pragma unroll
  for (int off = 32; off > 0; off >>= 1) v += __shfl_xor(v, off, 64);
  return v;
}
__device__ __forceinline__ double wmin(double v) {
#pragma unroll
  for (int off = 32; off > 0; off >>= 1) v = fmin(v, __shfl_xor(v, off, 64));
  return v;
}
__device__ __forceinline__ double fair_c(int c) {
  return (c < 8) ? 0.125 : (double)(-1.0f / 12.0f);  // matches fp32 ref constant
}

__global__ __launch_bounds__(64, 1) void ipm_kernel(const float* __restrict__ x,
                                                    float* __restrict__ out) {
  const int b = blockIdx.x;
  const int t = threadIdx.x;

  __shared__ double zm[NN * NP];     // z (20x20, stride 21)
  __shared__ double dzm[NN * NP];
  __shared__ double phim[NN * NP];
  __shared__ double phiDm[NN * NP];  // phi * D1i[row]
  __shared__ double y1m[NN * NP];
  __shared__ double SmX[NN * SP];    // [S | rb1 rb2]
  __shared__ double glrc[40];        // lam+g for row/col constraints
  __shared__ double invd[40];        // s/lam for row/col constraints (1/d)
  __shared__ double rowsum[NN], colsum[NN];
  __shared__ double p1v[NN], t1v[NN], p2v[NN], Ccv[NN], D1iv[NN], D2vv[NN];
  __shared__ double be1v[NN], be2v[NN], a1rv[NN], a2rv[NN];

  const double EPSd = 1e-4, SIG = 0.1;

  // per-lane element state: element i = t + 64*j  (j = 0..6, i < 400)
  double zr[7], pr[7], fcr[7];
  double phir[7], y1r[7], w1r[7], w2r[7], dzr[7];
  // slack-constraint state (constraint 40+i, aligned with element i)
  double ss[7], sl[7], srs[7], srp[7], sds[7], sdl[7];
  int rr_[7], cc_[7];
  // row/col constraint state: constraint k = t, lanes t < 40 (rows 0..19, cols 20..39)
  double s1 = 0.5, l1 = 1.0, rs1, rp1, ds1, dl1;

#pragma unroll
  for (int j = 0; j < 7; ++j) {
    int i = t + 64 * j;
    if (i < N2) {
      int r = i / NN, c = i - r * NN;
      rr_[j] = r; cc_[j] = c;
      fcr[j] = fair_c(c);
      zr[j] = 0.025;
      pr[j] = -(double)x[b * N2 + i];
      zm[r * NP + c] = 0.025;
      ss[j] = 0.025;   // slack s for -z <= 0 constraint: h - Gz = 0 + z = 0.025
      sl[j] = 1.0;
    }
  }
  double nu = 0.0;
  FENCE();

#pragma unroll 1
  for (int it = 0; it < NITERS; ++it) {
    // ---- A: mu, r_eq, row/col sums of z
    double lmu = 0.0, lreq = 0.0;
#pragma unroll
    for (int j = 0; j < 7; ++j) {
      int i = t + 64 * j;
      if (i < N2) { lmu += ss[j] * sl[j]; lreq += fcr[j] * zr[j]; }
    }
    if (t < 40) lmu += s1 * l1;
    const double mu = wsum(lmu) * (1.0 / MM);
    const double req = wsum(lreq);
    const double smu = SIG * mu;
    if (t < NN) {
      double a = 0.0, c2 = 0.0;
#pragma unroll
      for (int jj = 0; jj < NN; ++jj) { a += zm[t * NP + jj]; c2 += zm[jj * NP + t]; }
      rowsum[t] = a; colsum[t] = c2;
    }
    FENCE();

    // ---- C: residuals, d, gl = lam + g = smu/s + d*r_pri
    if (t < 40) {
      rs1 = drcp(s1);
      double d = l1 * rs1;
      double gz = (t < NN) ? rowsum[t] : colsum[t - NN];
      rp1 = gz + s1 - 1.0;
      glrc[t] = smu * rs1 + d * rp1;
      invd[t] = s1 * drcp(l1);
    }
    double dslk[7];
#pragma unroll
    for (int j = 0; j < 7; ++j) {
      int i = t + 64 * j;
      if (i < N2) {
        double rs = drcp(ss[j]);
        srs[j] = rs;
        double d = sl[j] * rs;
        dslk[j] = d;
        srp[j] = ss[j] - zr[j];              // gz = -z, h = 0
        phir[j] = drcp(EPSd + d);
      }
    }
    FENCE();

    // ---- D: y1 = rhs_z (uses glrc), store phi/y1 tiles
#pragma unroll
    for (int j = 0; j < 7; ++j) {
      int i = t + 64 * j;
      if (i < N2) {
        int r = rr_[j], c = cc_[j];
        double gl_own = smu * srs[j] + dslk[j] * srp[j];  // lam+g for slack 40+i
        double y = -(EPSd * zr[j] + pr[j] + nu * fcr[j]
                     + glrc[r] + glrc[NN + c] - gl_own);
        phim[r * NP + c] = phir[j];
        y1r[j] = y;
        y1m[r * NP + c] = y;
      }
    }
    FENCE();

    // ---- E: row/col reductions over phi
    if (t < NN) {
      double R = 0.0, C = 0.0, P1 = 0.0, T1 = 0.0, P2 = 0.0;
#pragma unroll
      for (int jj = 0; jj < NN; ++jj) {
        double phr = phim[t * NP + jj];
        double phc = phim[jj * NP + t];
        R += phr; C += phc;
        P1 += phr * y1m[t * NP + jj];
        T1 += phc * y1m[jj * NP + t];
        P2 += phr * fair_c(jj);
      }
      D1iv[t] = drcp(invd[t] + R);            // 1/(1/d_row + R)
      Ccv[t] = C;
      D2vv[t] = invd[NN + t] + C;             // 1/d_col + C
      p1v[t] = P1; t1v[t] = T1; p2v[t] = P2;
    }
    FENCE();

    // ---- F: phiD = phi * D1i[row]
#pragma unroll
    for (int j = 0; j < 7; ++j) {
      int i = t + 64 * j;
      if (i < N2) phiDm[rr_[j] * NP + cc_[j]] = phir[j] * D1iv[rr_[j]];
    }
    FENCE();

    // ---- G: Schur S = D2 - Phi^T D1^-1 Phi (all 400), + rb1/rb2
#pragma unroll
    for (int j = 0; j < 7; ++j) {
      int e = t + 64 * j;
      if (e < N2) {
        int c = e / NN, cp = e - c * NN;
        double acc = 0.0;
#pragma unroll
        for (int r = 0; r < NN; ++r) acc += phiDm[r * NP + c] * phim[r * NP + cp];
        double Sv = -acc;
        if (c == cp) Sv += D2vv[c];
        SmX[c * SP + cp] = Sv;
      }
    }
    if (t < NN) {
      double a1 = 0.0, a2 = 0.0;
#pragma unroll
      for (int r = 0; r < NN; ++r) {
        double pd = phiDm[r * NP + t];
        a1 += pd * p1v[r];
        a2 += pd * p2v[r];
      }
      SmX[t * SP + NN] = t1v[t] - a1;                 // rb1
      SmX[t * SP + NN + 1] = fair_c(t) * Ccv[t] - a2; // rb2
    }
    FENCE();

    // ---- H: in-wave Gauss-Jordan; lanes 0..19 own S columns, 20/21 RHS
    {
      double B[NN];
#pragma unroll
      for (int i = 0; i < NN; ++i) {
        double v = 0.0;
        if (t < NN + 2) v = SmX[i * SP + t];
        B[i] = v;
      }
#pragma unroll
      for (int k = 0; k < NN; ++k) {
        double piv = __shfl(B[k], k, 64);
        double dinv = drcp(piv);
        double colk[NN];
#pragma unroll
        for (int i = 0; i < NN; ++i) colk[i] = __shfl(B[i], k, 64);
        double rk = B[k] * dinv;
#pragma unroll
        for (int i = 0; i < NN; ++i)
          if (i != k) B[i] -= colk[i] * rk;
        B[k] = rk;
      }
      if (t == NN) {
#pragma unroll
        for (int i = 0; i < NN; ++i) be1v[i] = B[i];
      }
      if (t == NN + 1) {
#pragma unroll
        for (int i = 0; i < NN; ++i) be2v[i] = B[i];
      }
    }
    FENCE();

    // ---- I: alpha_row = D1i * (p - Phi beta)
    if (t < NN) {
      double a1 = 0.0, a2 = 0.0;
#pragma unroll
      for (int c = 0; c < NN; ++c) {
        double ph = phim[t * NP + c];
        a1 += ph * be1v[c];
        a2 += ph * be2v[c];
      }
      a1rv[t] = (p1v[t] - a1) * D1iv[t];
      a2rv[t] = (p2v[t] - a2) * D1iv[t];
    }
    FENCE();

    // ---- J: w1 = H^-1 y1, w2 = H^-1 a; dnu
    double l1d = 0.0, l2d = 0.0;
#pragma unroll
    for (int j = 0; j < 7; ++j) {
      int i = t + 64 * j;
      if (i < N2) {
        int r = rr_[j], c = cc_[j];
        double w1 = phir[j] * (y1r[j] - a1rv[r] - be1v[c]);
        double w2 = phir[j] * (fcr[j] - a2rv[r] - be2v[c]);
        w1r[j] = w1; w2r[j] = w2;
        l1d += fcr[j] * w1; l2d += fcr[j] * w2;
      }
    }
    l1d = wsum(l1d);
    l2d = wsum(l2d);
    const double dnu = (l1d + req) * drcp(l2d);

    // ---- K: dz
#pragma unroll
    for (int j = 0; j < 7; ++j) {
      int i = t + 64 * j;
      if (i < N2) {
        double d = w1r[j] - dnu * w2r[j];
        dzr[j] = d;
        dzm[rr_[j] * NP + cc_[j]] = d;
      }
    }
    FENCE();

    // ---- L: row/col sums of dz
    if (t < NN) {
      double a = 0.0, c2 = 0.0;
#pragma unroll
      for (int jj = 0; jj < NN; ++jj) { a += dzm[t * NP + jj]; c2 += dzm[jj * NP + t]; }
      rowsum[t] = a; colsum[t] = c2;
    }
    FENCE();

    // ---- M: ds, dlam, step length
    double lmin = 1e30;
    if (t < 40) {
      double gdz = (t < NN) ? rowsum[t] : colsum[t - NN];
      ds1 = -rp1 - gdz;
      dl1 = (smu - s1 * l1 - l1 * ds1) * rs1;
      if (ds1 < 0.0) lmin = fmin(lmin, -s1 * drcp(ds1));
      if (dl1 < 0.0) lmin = fmin(lmin, -l1 * drcp(dl1));
    }
#pragma unroll
    for (int j = 0; j < 7; ++j) {
      int i = t + 64 * j;
      if (i < N2) {
        double ds = -srp[j] + dzr[j];          // gdz = -dz
        double dl = (smu - ss[j] * sl[j] - sl[j] * ds) * srs[j];
        sds[j] = ds; sdl[j] = dl;
        if (ds < 0.0) lmin = fmin(lmin, -ss[j] * drcp(ds));
        if (dl < 0.0) lmin = fmin(lmin, -sl[j] * drcp(dl));
      }
    }
    lmin = wmin(lmin);
    const double alpha = fmin(1.0, 0.99 * lmin);

    // ---- N: updates
#pragma unroll
    for (int j = 0; j < 7; ++j) {
      int i = t + 64 * j;
      if (i < N2) {
        zr[j] += alpha * dzr[j];
        zm[rr_[j] * NP + cc_[j]] = zr[j];
        ss[j] += alpha * sds[j];
        sl[j] += alpha * sdl[j];
      }
    }
    if (t < 40) { s1 += alpha * ds1; l1 += alpha * dl1; }
    nu += alpha * dnu;
    FENCE();
  }

#pragma unroll
  for (int j = 0; j < 7; ++j) {
    int i = t + 64 * j;
    if (i < N2) out[b * N2 + i] = (float)zr[j];
  }
}

extern "C" void kernel_launch(void* const* d_in, const int* in_sizes, int n_in,
                              void* d_out, int out_size, void* d_ws, size_t ws_size,
                              hipStream_t stream) {
  const float* x = (const float*)d_in[0];
  float* out = (float*)d_out;
  hipLaunchKernelGGL(ipm_kernel, dim3(32), dim3(64), 0, stream, x, out);
}

// Round 4
// 354.263 us; speedup vs baseline: 1.5367x; 1.2807x over previous
//
#include <hip/hip_runtime.h>

#define NN 20
#define NP 21          // padded stride for 20x20 fp64 tiles (2-way conflicts only = free)
#define SP 22          // Schur stride: cols 0..19 = S, 20 = rb1, 21 = rb2
#define N2 400
#define MM 440
#define NITERS 25

// single-wave block + per-wave in-order LDS pipeline => compiler fence suffices
#define FENCE() asm volatile("" ::: "memory")

__device__ __forceinline__ double drcp(double x) {
  double r = __builtin_amdgcn_rcp(x);       // v_rcp_f64 approx
  r = fma(r, fma(-x, r, 1.0), r);           // NR 1
  r = fma(r, fma(-x, r, 1.0), r);           // NR 2 -> ~1 ulp
  return r;
}
__device__ __forceinline__ double dreadlane(double v, int lane) {
  int lo = __builtin_amdgcn_readlane(__double2loint(v), lane);
  int hi = __builtin_amdgcn_readlane(__double2hiint(v), lane);
  return __hiloint2double(hi, lo);
}
__device__ __forceinline__ double wsum(double v) {
#pragma unroll
  for (int off = 32; off > 0; off >>= 1) v += __shfl_xor(v, off, 64);
  return v;
}
__device__ __forceinline__ double wmin(double v) {
#pragma unroll
  for (int off = 32; off > 0; off >>= 1) v = fmin(v, __shfl_xor(v, off, 64));
  return v;
}
__device__ __forceinline__ double fair_c(int c) {
  return (c < 8) ? 0.125 : (double)(-1.0f / 12.0f);  // matches fp32 ref constant
}

__global__ __launch_bounds__(64, 1) void ipm_kernel(const float* __restrict__ x,
                                                    float* __restrict__ out) {
  const int b = blockIdx.x;
  const int t = threadIdx.x;

  __shared__ double phim[NN * NP];
  __shared__ double y1m[NN * NP];
  __shared__ double phiDm[NN * NP];
  __shared__ double SmX[NN * SP];    // [S | rb1 rb2]
  __shared__ double glrc[40];
  __shared__ double D1iv[NN], D2vv[NN], p1v[NN], p2v[NN], t1v[NN], Ccv[NN];
  __shared__ double a1G[NN], a2G[NN];
  __shared__ double be1v[NN], be2v[NN], a1rv[NN], a2rv[NN], PB1v[NN], PB2v[NN];

  const double EPSd = 1e-4, SIG = 0.1;

  // per-lane element state: element i = t + 64*j (j = 0..6, i < 400)
  double zr[7], pr[7], fcr[7];
  double phir[7], y1r[7], glsl[7], w1r[7], w2r[7], dzr[7];
  double ss[7], sl[7], srs[7], srp[7], sds[7], sdl[7];
  int rr_[7], cc_[7];
  // row/col constraint state: constraint k = t (t<20 rows, 20..39 cols)
  double s1 = 0.5, l1 = 1.0, sum1 = 0.5;   // sum1 = running row/col sum of z
  double rs1 = 0.0, rp1 = 0.0, ds1 = 0.0, dl1 = 0.0, invdloc = 0.0;
  double e0 = 0.0, e1 = 0.0, e2 = 0.0;     // R/C, P1/T1, P2
  double D1iloc = 0.0, PB1 = 0.0, PB2 = 0.0, a1rloc = 0.0, a2rloc = 0.0;
  double W1 = 0.0, W2 = 0.0, sumdz = 0.0;

  double lreq0 = 0.0;
#pragma unroll
  for (int j = 0; j < 7; ++j) {
    int i = t + 64 * j;
    if (i < N2) {
      int r = i / NN, c = i - r * NN;
      rr_[j] = r; cc_[j] = c;
      fcr[j] = fair_c(c);
      zr[j] = 0.025;
      pr[j] = -(double)x[b * N2 + i];
      ss[j] = 0.025;
      sl[j] = 1.0;
      lreq0 += fcr[j] * 0.025;
    }
  }
  double req = wsum(lreq0);   // uniform on all lanes
  double nu = 0.0;

#pragma unroll 1
  for (int it = 0; it < NITERS; ++it) {
    // ---- A: mu (only remaining global reduction at iteration head)
    double lmu = 0.0;
#pragma unroll
    for (int j = 0; j < 7; ++j) {
      int i = t + 64 * j;
      if (i < N2) lmu += ss[j] * sl[j];
    }
    if (t < 40) lmu += s1 * l1;
    const double mu = wsum(lmu) * (1.0 / MM);
    const double smu = SIG * mu;

    // ---- C: residuals & gl for row/col (register sums!) and slack constraints
    if (t < 40) {
      rs1 = drcp(s1);
      double d1 = l1 * rs1;
      rp1 = sum1 + s1 - 1.0;
      glrc[t] = smu * rs1 + d1 * rp1;
      invdloc = s1 * drcp(l1);
    }
#pragma unroll
    for (int j = 0; j < 7; ++j) {
      int i = t + 64 * j;
      if (i < N2) {
        double rs = drcp(ss[j]);
        srs[j] = rs;
        double d = sl[j] * rs;
        srp[j] = ss[j] - zr[j];                 // r_pri for slack: -z + s - 0
        glsl[j] = smu * rs + d * srp[j];
        phir[j] = drcp(EPSd + d);
      }
    }
    FENCE();

    // ---- D: y1 = rhs_z; store phi/y1 tiles
#pragma unroll
    for (int j = 0; j < 7; ++j) {
      int i = t + 64 * j;
      if (i < N2) {
        int r = rr_[j], c = cc_[j];
        double y = -(EPSd * zr[j] + pr[j] + nu * fcr[j]
                     + glrc[r] + glrc[NN + c] - glsl[j]);
        y1r[j] = y;
        phim[r * NP + c] = phir[j];
        y1m[r * NP + c] = y;
      }
    }
    FENCE();

    // ---- E: fused row (lanes 0..19) / col (lanes 20..39) reductions over phi,y1
    if (t < 40) {
      const bool isrow = (t < NN);
      const int base = isrow ? t * NP : (t - NN);
      const int strd = isrow ? 1 : NP;
      double a0 = 0.0, a1 = 0.0, a2 = 0.0;
#pragma unroll
      for (int jj = 0; jj < NN; ++jj) {
        double ph = phim[base + jj * strd];
        double yy = y1m[base + jj * strd];
        a0 += ph;
        a1 = fma(ph, yy, a1);
        a2 = fma(ph, fair_c(jj), a2);
      }
      e0 = a0; e1 = a1; e2 = a2;
      if (isrow) {
        D1iloc = drcp(invdloc + a0);
        D1iv[t] = D1iloc; p1v[t] = a1; p2v[t] = a2;
      } else {
        D2vv[t - NN] = invdloc + a0;
        t1v[t - NN] = a1; Ccv[t - NN] = a0;
      }
    }
    FENCE();

    // ---- F: phiD = phi * D1i[row]
#pragma unroll
    for (int j = 0; j < 7; ++j) {
      int i = t + 64 * j;
      if (i < N2) phiDm[rr_[j] * NP + cc_[j]] = phir[j] * D1iv[rr_[j]];
    }
    FENCE();

    // ---- G: Schur S = D2 - Phi^T D1^-1 Phi, rb1/rb2, a1G/a2G
#pragma unroll
    for (int j = 0; j < 7; ++j) {
      int e = t + 64 * j;
      if (e < N2) {
        int c = e / NN, cp = e - c * NN;
        double acc = 0.0;
#pragma unroll
        for (int r = 0; r < NN; ++r) acc = fma(phiDm[r * NP + c], phim[r * NP + cp], acc);
        double dg = 0.0;
        if (c == cp) dg = D2vv[c];
        SmX[c * SP + cp] = dg - acc;
      }
    }
    if (t < NN) {
      double a1 = 0.0, a2 = 0.0;
#pragma unroll
      for (int r = 0; r < NN; ++r) {
        double pd = phiDm[r * NP + t];
        a1 = fma(pd, p1v[r], a1);
        a2 = fma(pd, p2v[r], a2);
      }
      a1G[t] = a1; a2G[t] = a2;
      SmX[t * SP + NN] = t1v[t] - a1;
      SmX[t * SP + NN + 1] = fair_c(t) * Ccv[t] - a2;
    }
    FENCE();

    // ---- H: Gauss-Jordan via v_readlane (no LDS pipe in the 20-step chain)
    {
      double B[NN];
#pragma unroll
      for (int i = 0; i < NN; ++i) {
        double v = 0.0;
        if (t < NN + 2) v = SmX[i * SP + t];
        B[i] = v;
      }
#pragma unroll
      for (int k = 0; k < NN; ++k) {
        double piv = dreadlane(B[k], k);
        double dinv = drcp(piv);
        double rk = B[k] * dinv;
#pragma unroll
        for (int i = 0; i < NN; ++i) {
          if (i != k) {
            double ck = dreadlane(B[i], k);   // read-before-write per i: snapshot semantics
            B[i] = fma(-ck, rk, B[i]);
          }
        }
        B[k] = rk;
      }
      if (t == NN || t == NN + 1) {
        double* dst = (t == NN) ? be1v : be2v;
#pragma unroll
        for (int i = 0; i < NN; ++i) dst[i] = B[i];
      }
    }
    FENCE();

    // ---- I: row-lane back-substitution pieces: PB, a_row, W-row
    if (t < NN) {
      double b1 = 0.0, b2 = 0.0;
#pragma unroll
      for (int c = 0; c < NN; ++c) {
        double ph = phim[t * NP + c];
        b1 = fma(ph, be1v[c], b1);
        b2 = fma(ph, be2v[c], b2);
      }
      PB1 = b1; PB2 = b2;
      a1rloc = (e1 - b1) * D1iloc;
      a2rloc = (e2 - b2) * D1iloc;
      a1rv[t] = a1rloc; a2rv[t] = a2rloc;
      PB1v[t] = b1; PB2v[t] = b2;
      W1 = e1 - e0 * a1rloc - b1;              // rowsum(w1)
      W2 = e2 - e0 * a2rloc - b2;              // rowsum(w2)
    }
    FENCE();

    // ---- J: w1/w2 per element; col-lane W; dnu
    double l1d = 0.0, l2d = 0.0;
#pragma unroll
    for (int j = 0; j < 7; ++j) {
      int i = t + 64 * j;
      if (i < N2) {
        int r = rr_[j], c = cc_[j];
        double w1 = phir[j] * (y1r[j] - a1rv[r] - be1v[c]);
        double w2 = phir[j] * (fcr[j] - a2rv[r] - be2v[c]);
        w1r[j] = w1; w2r[j] = w2;
        l1d = fma(fcr[j], w1, l1d);
        l2d = fma(fcr[j], w2, l2d);
      }
    }
    if (t >= NN && t < 2 * NN) {
      int c = t - NN;
      double accA1 = 0.0, accA2 = 0.0;
#pragma unroll
      for (int r = 0; r < NN; ++r) {
        double pd = phiDm[r * NP + c];
        accA1 = fma(pd, PB1v[r], accA1);
        accA2 = fma(pd, PB2v[r], accA2);
      }
      double A1 = a1G[c] - accA1;              // sum_r phiD[r,c]*a1r[r]... = A1c
      double A2 = a2G[c] - accA2;
      W1 = e1 - A1 - e0 * be1v[c];             // colsum(w1)
      W2 = e0 * fair_c(c) - A2 - e0 * be2v[c]; // colsum(w2)
    }
    l1d = wsum(l1d);
    l2d = wsum(l2d);
    const double dnu = (l1d + req) * drcp(l2d);
    if (t < 40) sumdz = W1 - dnu * W2;         // row/col sums of dz, in registers

    // ---- K: dz per element (registers only)
#pragma unroll
    for (int j = 0; j < 7; ++j) {
      int i = t + 64 * j;
      if (i < N2) dzr[j] = w1r[j] - dnu * w2r[j];
    }

    // ---- M: ds, dlam, step length (no LDS)
    double lmin = 1e30;
    if (t < 40) {
      ds1 = -rp1 - sumdz;
      dl1 = (smu - s1 * l1 - l1 * ds1) * rs1;
      if (ds1 < 0.0) lmin = fmin(lmin, -s1 * drcp(ds1));
      if (dl1 < 0.0) lmin = fmin(lmin, -l1 * drcp(dl1));
    }
#pragma unroll
    for (int j = 0; j < 7; ++j) {
      int i = t + 64 * j;
      if (i < N2) {
        double ds = -srp[j] + dzr[j];          // G_slack*dz = -dz
        double dl = (smu - ss[j] * sl[j] - sl[j] * ds) * srs[j];
        sds[j] = ds; sdl[j] = dl;
        if (ds < 0.0) lmin = fmin(lmin, -ss[j] * drcp(ds));
        if (dl < 0.0) lmin = fmin(lmin, -sl[j] * drcp(dl));
      }
    }
    lmin = wmin(lmin);
    const double alpha = fmin(1.0, 0.99 * lmin);

    // ---- N: updates (all in registers; exact recurrences for sums)
#pragma unroll
    for (int j = 0; j < 7; ++j) {
      int i = t + 64 * j;
      if (i < N2) {
        zr[j] += alpha * dzr[j];
        ss[j] += alpha * sds[j];
        sl[j] += alpha * sdl[j];
      }
    }
    if (t < 40) {
      s1 += alpha * ds1;
      l1 += alpha * dl1;
      sum1 += alpha * sumdz;                   // rowsum/colsum(z) recurrence (exact)
    }
    nu += alpha * dnu;
    req *= (1.0 - alpha);                      // r_eq recurrence (exact)
    FENCE();
  }

#pragma unroll
  for (int j = 0; j < 7; ++j) {
    int i = t + 64 * j;
    if (i < N2) out[b * N2 + i] = (float)zr[j];
  }
}

extern "C" void kernel_launch(void* const* d_in, const int* in_sizes, int n_in,
                              void* d_out, int out_size, void* d_ws, size_t ws_size,
                              hipStream_t stream) {
  const float* x = (const float*)d_in[0];
  float* out = (float*)d_out;
  hipLaunchKernelGGL(ipm_kernel, dim3(32), dim3(64), 0, stream, x, out);
}

// Round 6
// 337.465 us; speedup vs baseline: 1.6132x; 1.0498x over previous
//
#include <hip/hip_runtime.h>

#define NN 20
#define ST 22          // stride for all 20-row fp64 tiles; rows 16B-aligned (b128-friendly)
#define N2 400
#define MM 440
#define NITERS 25

// single-wave block + per-wave in-order LDS pipeline => compiler fence suffices
#define FENCE() asm volatile("" ::: "memory")

__device__ __forceinline__ double drcp(double x) {
  double r = __builtin_amdgcn_rcp(x);       // v_rcp_f64 seed
  r = fma(r, fma(-x, r, 1.0), r);           // NR 1
  r = fma(r, fma(-x, r, 1.0), r);           // NR 2 -> ~1 ulp
  return r;
}
__device__ __forceinline__ double dreadlane(double v, int lane) {
  int lo = __builtin_amdgcn_readlane(__double2loint(v), lane);
  int hi = __builtin_amdgcn_readlane(__double2hiint(v), lane);
  return __hiloint2double(hi, lo);
}
__device__ __forceinline__ double wsumd(double v) {
#pragma unroll
  for (int off = 32; off > 0; off >>= 1) v += __shfl_xor(v, off, 64);
  return v;
}
__device__ __forceinline__ double wmind(double v) {
#pragma unroll
  for (int off = 32; off > 0; off >>= 1) v = fmin(v, __shfl_xor(v, off, 64));
  return v;
}
__device__ __forceinline__ double fair_d(int c) {
  return (c < 8) ? 0.125 : (double)(-1.0f / 12.0f);  // matches fp32 ref constant
}

__global__ __launch_bounds__(64, 1) void ipm_kernel(const float* __restrict__ x,
                                                    float* __restrict__ out) {
  const int b = blockIdx.x;
  const int t = threadIdx.x;

  __shared__ __align__(16) double phim[NN * ST];   // phi, row-major
  __shared__ __align__(16) double phimT[NN * ST];  // phi transposed
  __shared__ __align__(16) double y1m[NN * ST];
  __shared__ __align__(16) double y1T[NN * ST];
  __shared__ __align__(16) double phiDT[NN * ST];  // (phi * D1i[row]) transposed
  __shared__ __align__(16) double SmX[NN * ST];    // row c: [ S[c][0..19] | rb1[c] rb2[c] ]
  __shared__ __align__(16) double glrc[40];
  __shared__ __align__(16) double D1iv[NN], D2vv[NN];
  __shared__ __align__(16) double p1v[NN], p2v[NN], t1v[NN], Ccv[NN];
  __shared__ __align__(16) double a1G[NN], a2G[NN];
  __shared__ __align__(16) double be1v[NN], be2v[NN];
  __shared__ __align__(16) double a1rv[NN], a2rv[NN], PB1v[NN], PB2v[NN];

  const double EPSd = 1e-4, SIG = 0.1;

  // element state: element i = t + 64*j (j=0..6)
  double zr[7], pr[7], fcr[7];
  double phir[7], y1r[7], glsl[7], w1r[7], w2r[7], dzr[7];
  double ss[7], sl[7], srs[7], srp[7], sds[7], sdl[7];
  int rr_[7], cc_[7];
  // row/col constraint state on lanes t<40 (rows 0..19, cols 20..39)
  double s1 = 0.5, l1 = 1.0, sum1 = 0.5;   // sum1 = running row/col sum of z
  double rs1 = 0.0, rp1 = 0.0, ds1 = 0.0, dl1 = 0.0, invdloc = 0.0;
  double e0 = 0.0, e1 = 0.0, e2 = 0.0;
  double D1iloc = 0.0, PB1 = 0.0, PB2 = 0.0, a1rloc = 0.0, a2rloc = 0.0;
  double W1 = 0.0, W2 = 0.0, sumdz = 0.0;

  double lreq0 = 0.0;
#pragma unroll
  for (int j = 0; j < 7; ++j) {
    int i = t + 64 * j;
    if (i < N2) {
      int r = i / NN, c = i - r * NN;
      rr_[j] = r; cc_[j] = c;
      fcr[j] = fair_d(c);
      zr[j] = 0.025;
      pr[j] = -(double)x[b * N2 + i];
      ss[j] = 0.025;
      sl[j] = 1.0;
      lreq0 += fcr[j] * 0.025;
    }
  }
  double req = wsumd(lreq0);
  double nu = 0.0;

#pragma unroll 1
  for (int it = 0; it < NITERS; ++it) {
    // ---- A: mu
    double lmu = 0.0;
#pragma unroll
    for (int j = 0; j < 7; ++j) {
      int i = t + 64 * j;
      if (i < N2) lmu += ss[j] * sl[j];
    }
    if (t < 40) lmu += s1 * l1;
    const double mu = wsumd(lmu) * (1.0 / MM);
    const double smu = SIG * mu;

    // ---- C: residuals & gl
    if (t < 40) {
      rs1 = drcp(s1);
      double d1 = l1 * rs1;
      rp1 = sum1 + s1 - 1.0;
      glrc[t] = smu * rs1 + d1 * rp1;
      invdloc = s1 * drcp(l1);              // 1/d = s/lam
    }
#pragma unroll
    for (int j = 0; j < 7; ++j) {
      int i = t + 64 * j;
      if (i < N2) {
        double rs = drcp(ss[j]);
        srs[j] = rs;
        double d = sl[j] * rs;
        srp[j] = ss[j] - zr[j];             // r_pri for slack: -z + s - 0
        glsl[j] = smu * rs + d * srp[j];
        phir[j] = drcp(EPSd + d);
      }
    }
    FENCE();

    // ---- D: y1 = rhs_z; store row-major + transposed tiles
#pragma unroll
    for (int j = 0; j < 7; ++j) {
      int i = t + 64 * j;
      if (i < N2) {
        int r = rr_[j], c = cc_[j];
        double y = -(EPSd * zr[j] + pr[j] + nu * fcr[j]
                     + glrc[r] + glrc[NN + c] - glsl[j]);
        y1r[j] = y;
        phim[r * ST + c] = phir[j];
        phimT[c * ST + r] = phir[j];
        y1m[r * ST + c] = y;
        y1T[c * ST + r] = y;
      }
    }
    FENCE();

    // ---- E: fused row (0..19) / col (20..39) reductions, contiguous double2 reads
    if (t < 40) {
      const bool isrow = (t < NN);
      const double2* pb = reinterpret_cast<const double2*>(isrow ? &phim[t * ST] : &phimT[(t - NN) * ST]);
      const double2* yb = reinterpret_cast<const double2*>(isrow ? &y1m[t * ST] : &y1T[(t - NN) * ST]);
      double a0A = 0.0, a0B = 0.0, a1A = 0.0, a1B = 0.0, a2A = 0.0, a2B = 0.0;
#pragma unroll
      for (int jj = 0; jj < 10; ++jj) {
        double2 ph = pb[jj];
        double2 yy = yb[jj];
        a0A += ph.x;                 a0B += ph.y;
        a1A = fma(ph.x, yy.x, a1A);  a1B = fma(ph.y, yy.y, a1B);
        a2A = fma(ph.x, fair_d(2 * jj), a2A);
        a2B = fma(ph.y, fair_d(2 * jj + 1), a2B);
      }
      e0 = a0A + a0B; e1 = a1A + a1B; e2 = a2A + a2B;
      if (isrow) {
        D1iloc = drcp(invdloc + e0);
        D1iv[t] = D1iloc; p1v[t] = e1; p2v[t] = e2;
      } else {
        D2vv[t - NN] = invdloc + e0;
        t1v[t - NN] = e1; Ccv[t - NN] = e0;
      }
    }
    FENCE();

    // ---- F: phiDT = (phi * D1i[row])^T
#pragma unroll
    for (int j = 0; j < 7; ++j) {
      int i = t + 64 * j;
      if (i < N2) phiDT[cc_[j] * ST + rr_[j]] = phir[j] * D1iv[rr_[j]];
    }
    FENCE();

    // ---- G: Schur S = D2 - Phi^T D1^-1 Phi (all 400), rb1/rb2, a1G/a2G
#pragma unroll
    for (int j = 0; j < 7; ++j) {
      int e = t + 64 * j;
      if (e < N2) {
        int c = e / NN, cp = e - c * NN;
        const double2* pa = reinterpret_cast<const double2*>(&phiDT[c * ST]);
        const double2* pbb = reinterpret_cast<const double2*>(&phimT[cp * ST]);
        double accA = 0.0, accB = 0.0;
#pragma unroll
        for (int r = 0; r < 10; ++r) {
          double2 u = pa[r], v = pbb[r];
          accA = fma(u.x, v.x, accA);
          accB = fma(u.y, v.y, accB);
        }
        double Sv = -(accA + accB);
        if (c == cp) Sv += D2vv[c];
        SmX[c * ST + cp] = Sv;
      }
    }
    if (t < NN) {
      const double2* pa = reinterpret_cast<const double2*>(&phiDT[t * ST]);
      const double2* q1 = reinterpret_cast<const double2*>(p1v);
      const double2* q2 = reinterpret_cast<const double2*>(p2v);
      double a1A = 0.0, a1B = 0.0, a2A = 0.0, a2B = 0.0;
#pragma unroll
      for (int r = 0; r < 10; ++r) {
        double2 u = pa[r];
        double2 w1 = q1[r], w2 = q2[r];
        a1A = fma(u.x, w1.x, a1A); a1B = fma(u.y, w1.y, a1B);
        a2A = fma(u.x, w2.x, a2A); a2B = fma(u.y, w2.y, a2B);
      }
      double g1 = a1A + a1B, g2 = a2A + a2B;
      a1G[t] = g1; a2G[t] = g2;
      SmX[t * ST + NN] = t1v[t] - g1;                 // rb1
      SmX[t * ST + NN + 1] = fair_d(t) * Ccv[t] - g2; // rb2
    }
    FENCE();

    // ---- H: Gauss-Jordan; lane t owns column t; pivot rcp software-pipelined
    {
      double B[NN];
#pragma unroll
      for (int i = 0; i < NN; ++i) B[i] = (t < NN + 2) ? SmX[i * ST + t] : 0.0;
      double dinv;
      { double piv = dreadlane(B[0], 0); dinv = drcp(piv); }
#pragma unroll
      for (int k = 0; k < NN; ++k) {
        double rk = B[k] * dinv;
        if (k < NN - 1) {
          // row k+1 gets its step-k update first; next pivot's rcp latency hides below
          double ck1 = dreadlane(B[k + 1], k);
          B[k + 1] = fma(-ck1, rk, B[k + 1]);
          double piv1 = dreadlane(B[k + 1], k + 1);
          dinv = drcp(piv1);
        }
#pragma unroll
        for (int i = 0; i < NN; ++i) {
          if (i != k && !(k < NN - 1 && i == k + 1)) {
            double ck = dreadlane(B[i], k);            // pre-step column-k value
            B[i] = fma(-ck, rk, B[i]);
          }
        }
        B[k] = rk;
      }
      if (t == NN || t == NN + 1) {
        double* dst = (t == NN) ? be1v : be2v;
#pragma unroll
        for (int i = 0; i < NN; ++i) dst[i] = B[i];
      }
    }
    FENCE();

    // ---- I: row-lane pieces: PB, a_row, row W
    if (t < NN) {
      const double2* pa = reinterpret_cast<const double2*>(&phim[t * ST]);
      const double2* q1 = reinterpret_cast<const double2*>(be1v);
      const double2* q2 = reinterpret_cast<const double2*>(be2v);
      double b1A = 0.0, b1B = 0.0, b2A = 0.0, b2B = 0.0;
#pragma unroll
      for (int c = 0; c < 10; ++c) {
        double2 ph = pa[c];
        double2 w1 = q1[c], w2 = q2[c];
        b1A = fma(ph.x, w1.x, b1A); b1B = fma(ph.y, w1.y, b1B);
        b2A = fma(ph.x, w2.x, b2A); b2B = fma(ph.y, w2.y, b2B);
      }
      PB1 = b1A + b1B; PB2 = b2A + b2B;
      a1rloc = (e1 - PB1) * D1iloc;
      a2rloc = (e2 - PB2) * D1iloc;
      a1rv[t] = a1rloc; a2rv[t] = a2rloc;
      PB1v[t] = PB1; PB2v[t] = PB2;
      W1 = e1 - e0 * a1rloc - PB1;
      W2 = e2 - e0 * a2rloc - PB2;
    }
    FENCE();

    // ---- J: w1/w2 per element; col-lane W; dnu
    double l1d = 0.0, l2d = 0.0;
#pragma unroll
    for (int j = 0; j < 7; ++j) {
      int i = t + 64 * j;
      if (i < N2) {
        int r = rr_[j], c = cc_[j];
        double w1 = phir[j] * (y1r[j] - a1rv[r] - be1v[c]);
        double w2 = phir[j] * (fcr[j] - a2rv[r] - be2v[c]);
        w1r[j] = w1; w2r[j] = w2;
        l1d = fma(fcr[j], w1, l1d);
        l2d = fma(fcr[j], w2, l2d);
      }
    }
    if (t >= NN && t < 2 * NN) {
      int c = t - NN;
      const double2* pa = reinterpret_cast<const double2*>(&phiDT[c * ST]);
      const double2* q1 = reinterpret_cast<const double2*>(PB1v);
      const double2* q2 = reinterpret_cast<const double2*>(PB2v);
      double c1A = 0.0, c1B = 0.0, c2A = 0.0, c2B = 0.0;
#pragma unroll
      for (int r = 0; r < 10; ++r) {
        double2 u = pa[r];
        double2 w1 = q1[r], w2 = q2[r];
        c1A = fma(u.x, w1.x, c1A); c1B = fma(u.y, w1.y, c1B);
        c2A = fma(u.x, w2.x, c2A); c2B = fma(u.y, w2.y, c2B);
      }
      double A1 = a1G[c] - (c1A + c1B);
      double A2 = a2G[c] - (c2A + c2B);
      W1 = e1 - A1 - e0 * be1v[c];
      W2 = e0 * fair_d(c) - A2 - e0 * be2v[c];
    }
#pragma unroll
    for (int off = 32; off > 0; off >>= 1) {
      l1d += __shfl_xor(l1d, off, 64);
      l2d += __shfl_xor(l2d, off, 64);
    }
    const double dnu = (l1d + req) * drcp(l2d);
    if (t < 40) sumdz = W1 - dnu * W2;

    // ---- K: dz per element (registers only)
#pragma unroll
    for (int j = 0; j < 7; ++j) {
      int i = t + 64 * j;
      if (i < N2) dzr[j] = w1r[j] - dnu * w2r[j];
    }

    // ---- M: ds, dlam, step length (fp64, as R4)
    double lmin = 1e30;
    if (t < 40) {
      ds1 = -rp1 - sumdz;
      dl1 = (smu - s1 * l1 - l1 * ds1) * rs1;
      if (ds1 < 0.0) lmin = fmin(lmin, -s1 * drcp(ds1));
      if (dl1 < 0.0) lmin = fmin(lmin, -l1 * drcp(dl1));
    }
#pragma unroll
    for (int j = 0; j < 7; ++j) {
      int i = t + 64 * j;
      if (i < N2) {
        double ds = -srp[j] + dzr[j];          // G_slack*dz = -dz
        double dl = (smu - ss[j] * sl[j] - sl[j] * ds) * srs[j];
        sds[j] = ds; sdl[j] = dl;
        if (ds < 0.0) lmin = fmin(lmin, -ss[j] * drcp(ds));
        if (dl < 0.0) lmin = fmin(lmin, -sl[j] * drcp(dl));
      }
    }
    lmin = wmind(lmin);
    const double alpha = fmin(1.0, 0.99 * lmin);

    // ---- N: updates + exact recurrences
#pragma unroll
    for (int j = 0; j < 7; ++j) {
      int i = t + 64 * j;
      if (i < N2) {
        zr[j] = fma(alpha, dzr[j], zr[j]);
        ss[j] = fma(alpha, sds[j], ss[j]);
        sl[j] = fma(alpha, sdl[j], sl[j]);
      }
    }
    if (t < 40) {
      s1 = fma(alpha, ds1, s1);
      l1 = fma(alpha, dl1, l1);
      sum1 = fma(alpha, sumdz, sum1);          // rowsum/colsum(z) recurrence
    }
    nu = fma(alpha, dnu, nu);
    req *= (1.0 - alpha);                      // r_eq recurrence
    FENCE();
  }

#pragma unroll
  for (int j = 0; j < 7; ++j) {
    int i = t + 64 * j;
    if (i < N2) out[b * N2 + i] = (float)zr[j];
  }
}

extern "C" void kernel_launch(void* const* d_in, const int* in_sizes, int n_in,
                              void* d_out, int out_size, void* d_ws, size_t ws_size,
                              hipStream_t stream) {
  const float* x = (const float*)d_in[0];
  float* out = (float*)d_out;
  hipLaunchKernelGGL(ipm_kernel, dim3(32), dim3(64), 0, stream, x, out);
}